// Round 1
// baseline (867.750 us; speedup 1.0000x reference)
//
#include <hip/hip_runtime.h>

// out = [N, 2, 128] fp32 : {segment_max[row_ids[n]] - feat[n], feat[n]}
// N = in_sizes[0]/128, R = 50000 (problem constant; only used for ws memset size).

__device__ __forceinline__ unsigned int enc_f32(float f) {
    unsigned int u = __float_as_uint(f);
    return (u & 0x80000000u) ? ~u : (u | 0x80000000u);
}
__device__ __forceinline__ float dec_f32(unsigned int u) {
    unsigned int v = (u & 0x80000000u) ? (u & 0x7FFFFFFFu) : ~u;
    return __uint_as_float(v);
}

// Pass 1: scatter atomic-max. One thread per float4 chunk: n = i>>5, d4 = i&31.
__global__ void __launch_bounds__(256)
segmax_scatter(const float4* __restrict__ feat,
               const int* __restrict__ row_ids,
               unsigned int* __restrict__ segmax,  // [R*128] encoded
               int total_chunks) {
    int i = blockIdx.x * blockDim.x + threadIdx.x;
    if (i >= total_chunks) return;
    int n  = i >> 5;
    int d4 = i & 31;
    int row = row_ids[n];
    float4 f = feat[i];
    unsigned int e0 = enc_f32(f.x), e1 = enc_f32(f.y),
                 e2 = enc_f32(f.z), e3 = enc_f32(f.w);
    unsigned int* p = segmax + ((long long)row << 7) + (d4 << 2);
    // Pre-check: location is monotone non-decreasing in encode order, so a
    // skip based on any previously-written value is always safe.
    uint4 cur = *reinterpret_cast<const uint4*>(p);
    if (cur.x < e0) atomicMax(p + 0, e0);
    if (cur.y < e1) atomicMax(p + 1, e1);
    if (cur.z < e2) atomicMax(p + 2, e2);
    if (cur.w < e3) atomicMax(p + 3, e3);
}

// Pass 2: gather + emit [N][2][128] as [N][64] float4.
__global__ void __launch_bounds__(256)
gather_emit(const float4* __restrict__ feat,
            const int* __restrict__ row_ids,
            const uint4* __restrict__ segmax,   // [R*32] encoded float4
            float4* __restrict__ out,
            int total_chunks) {
    int i = blockIdx.x * blockDim.x + threadIdx.x;
    if (i >= total_chunks) return;
    int n  = i >> 5;
    int d4 = i & 31;
    int row = row_ids[n];
    float4 f = feat[i];
    uint4 m = segmax[((long long)row << 5) + d4];
    float4 r;
    r.x = dec_f32(m.x) - f.x;
    r.y = dec_f32(m.y) - f.y;
    r.z = dec_f32(m.z) - f.z;
    r.w = dec_f32(m.w) - f.w;
    long long ob = ((long long)n << 6) + d4;   // [N][64] float4
    out[ob]      = r;   // residual half  [n][0][d]
    out[ob + 32] = f;   // feat half      [n][1][d]
}

extern "C" void kernel_launch(void* const* d_in, const int* in_sizes, int n_in,
                              void* d_out, int out_size, void* d_ws, size_t ws_size,
                              hipStream_t stream) {
    const float* feat    = (const float*)d_in[0];
    const int*   row_ids = (const int*)d_in[1];
    // d_in[2] = num_rows (device scalar) — not needed on host; R fixed at 50000.
    const long long R = 50000;
    const int D = 128;
    const int N = in_sizes[0] / D;
    const int total_chunks = N * (D / 4);      // one float4 per thread

    // Zero-init encoded segmax table: 0 < enc(any float), safe identity.
    size_t seg_bytes = (size_t)R * D * sizeof(unsigned int);  // 25.6 MB
    if (seg_bytes > ws_size) seg_bytes = ws_size;              // defensive
    hipMemsetAsync(d_ws, 0, seg_bytes, stream);

    const int block = 256;
    const int grid  = (total_chunks + block - 1) / block;

    segmax_scatter<<<grid, block, 0, stream>>>(
        (const float4*)feat, row_ids, (unsigned int*)d_ws, total_chunks);

    gather_emit<<<grid, block, 0, stream>>>(
        (const float4*)feat, row_ids, (const uint4*)d_ws,
        (float4*)d_out, total_chunks);
}

// Round 2
// 866.540 us; speedup vs baseline: 1.0014x; 1.0014x over previous
//
#include <hip/hip_runtime.h>

// out = [N, 2, 128] fp32 : {segment_max[row_ids[n]] - feat[n], feat[n]}
// N = in_sizes[0]/128, R = 50000 (problem constant; used for ws init size).

__device__ __forceinline__ unsigned int enc_f32(float f) {
    unsigned int u = __float_as_uint(f);
    return (u & 0x80000000u) ? ~u : (u | 0x80000000u);
}
__device__ __forceinline__ float dec_f32(unsigned int u) {
    unsigned int v = (u & 0x80000000u) ? (u & 0x7FFFFFFFu) : ~u;
    return __uint_as_float(v);
}

// Pass 0: zero the encoded segmax table (enc(x) > 0 for every float, so 0 is
// a safe identity; only non-empty segments are ever gathered back).
// The rocclr blit fill ran at 42 GB/s inside the graph — do it ourselves.
__global__ void __launch_bounds__(256)
zero_fill(uint4* __restrict__ p, int n4) {
    int i = blockIdx.x * blockDim.x + threadIdx.x;
    int stride = gridDim.x * blockDim.x;
    uint4 z = {0u, 0u, 0u, 0u};
    for (; i < n4; i += stride) p[i] = z;
}

// Pass 1: scatter atomic-max. One thread per float4 chunk: n = i>>5, d4 = i&31.
__global__ void __launch_bounds__(256)
segmax_scatter(const float4* __restrict__ feat,
               const int* __restrict__ row_ids,
               unsigned int* __restrict__ segmax,  // [R*128] encoded
               int total_chunks) {
    int i = blockIdx.x * blockDim.x + threadIdx.x;
    if (i >= total_chunks) return;
    int n  = i >> 5;
    int d4 = i & 31;
    int row = row_ids[n];
    float4 f = feat[i];
    unsigned int e0 = enc_f32(f.x), e1 = enc_f32(f.y),
                 e2 = enc_f32(f.z), e3 = enc_f32(f.w);
    unsigned int* p = segmax + ((long long)row << 7) + (d4 << 2);
    // Pre-check: location is monotone non-decreasing in encode order, so a
    // skip based on any previously-visible value is always safe.
    uint4 cur = *reinterpret_cast<const uint4*>(p);
    if (cur.x < e0) atomicMax(p + 0, e0);
    if (cur.y < e1) atomicMax(p + 1, e1);
    if (cur.z < e2) atomicMax(p + 2, e2);
    if (cur.w < e3) atomicMax(p + 3, e3);
}

// Pass 2: gather + emit [N][2][128] as [N][64] float4.
__global__ void __launch_bounds__(256)
gather_emit(const float4* __restrict__ feat,
            const int* __restrict__ row_ids,
            const uint4* __restrict__ segmax,   // [R*32] encoded float4
            float4* __restrict__ out,
            int total_chunks) {
    int i = blockIdx.x * blockDim.x + threadIdx.x;
    if (i >= total_chunks) return;
    int n  = i >> 5;
    int d4 = i & 31;
    int row = row_ids[n];
    float4 f = feat[i];
    uint4 m = segmax[((long long)row << 5) + d4];
    float4 r;
    r.x = dec_f32(m.x) - f.x;
    r.y = dec_f32(m.y) - f.y;
    r.z = dec_f32(m.z) - f.z;
    r.w = dec_f32(m.w) - f.w;
    long long ob = ((long long)n << 6) + d4;   // [N][64] float4
    out[ob]      = r;   // residual half  [n][0][d]
    out[ob + 32] = f;   // feat half      [n][1][d]
}

extern "C" void kernel_launch(void* const* d_in, const int* in_sizes, int n_in,
                              void* d_out, int out_size, void* d_ws, size_t ws_size,
                              hipStream_t stream) {
    const float* feat    = (const float*)d_in[0];
    const int*   row_ids = (const int*)d_in[1];
    // d_in[2] = num_rows (device scalar) — R fixed at 50000 per problem.
    const long long R = 50000;
    const int D = 128;
    const int N = in_sizes[0] / D;
    const int total_chunks = N * (D / 4);      // one float4 per thread

    // Zero-init encoded segmax table with our own fill kernel.
    int seg_n4 = (int)(R * D / 4);             // 1.6M uint4 = 25.6 MB
    const int block = 256;
    int fill_grid = 2048;                      // grid-stride, ~256 CUs * 8
    zero_fill<<<fill_grid, block, 0, stream>>>((uint4*)d_ws, seg_n4);

    const int grid = (total_chunks + block - 1) / block;

    segmax_scatter<<<grid, block, 0, stream>>>(
        (const float4*)feat, row_ids, (unsigned int*)d_ws, total_chunks);

    gather_emit<<<grid, block, 0, stream>>>(
        (const float4*)feat, row_ids, (const uint4*)d_ws,
        (float4*)d_out, total_chunks);
}